// Round 1
// baseline (610.978 us; speedup 1.0000x reference)
//
#include <hip/hip_runtime.h>
#include <stdint.h>
#include <stddef.h>

#define D       256
#define KCODES  4096
#define NROWS   32768        // 16*2048
#define MTILE   128          // rows per block
#define WAVES   2
#define RPW     64           // rows per wave
#define KCHUNK  64
#define NCHUNK  (KCODES / KCHUNK)   // 64
#define NBLK    (NROWS / MTILE)     // 256

typedef __attribute__((ext_vector_type(8))) short short8;
typedef __attribute__((ext_vector_type(4))) float f32x4;
typedef __attribute__((ext_vector_type(4))) int   int4v;

__device__ inline unsigned int f2bf(float f) {
  union { float f; unsigned int u; } v; v.f = f;
  unsigned int r = v.u + 0x7FFFu + ((v.u >> 16) & 1u);   // RNE
  return r >> 16;
}

// ---- pass 1: codebook fp32 -> bf16, and ||c_k||^2 ----
__global__ void vq_prep(const float* __restrict__ cb,
                        unsigned short* __restrict__ cb16,
                        float* __restrict__ cnorm) {
  int row = blockIdx.x;         // 4096 blocks, one wave each
  int lane = threadIdx.x;       // 64
  float4 v = *(const float4*)(cb + (size_t)row * D + lane * 4);
  float s = v.x*v.x + v.y*v.y + v.z*v.z + v.w*v.w;
  uint2 p;
  p.x = f2bf(v.x) | (f2bf(v.y) << 16);
  p.y = f2bf(v.z) | (f2bf(v.w) << 16);
  *(uint2*)(cb16 + (size_t)row * D + lane * 4) = p;
#pragma unroll
  for (int o = 32; o; o >>= 1) s += __shfl_xor(s, o);
  if (lane == 0) cnorm[row] = s;
}

// ---- main: fused distance-GEMM + argmin + gather + loss partials ----
__global__ __launch_bounds__(128, 2) void vq_main(
    const float* __restrict__ latents,
    const unsigned short* __restrict__ cb16,
    const float* __restrict__ cnorm,
    const float* __restrict__ cb32,
    float* __restrict__ out,
    float* __restrict__ partials)
{
  __shared__ char  smem[32 * 1024];   // codebook chunk [64][256] bf16, XOR-swizzled
  __shared__ int   s_inds[MTILE];
  __shared__ float s_part[WAVES];

  const int t    = threadIdx.x;
  const int lane = t & 63;
  const int w    = t >> 6;
  const int blk  = blockIdx.x;
  const int rowbase = blk * MTILE;

  // A fragments straight from global (fp32 -> bf16), stay in regs all kernel.
  // MFMA 16x16x32 A layout: lane holds A[lane&15][(lane>>4)*8 + j], j=0..7.
  short8 afr[4][8];
  {
    const int r0 = rowbase + w * RPW + (lane & 15);
    const int kb = (lane >> 4) * 8;
#pragma unroll
    for (int rt = 0; rt < 4; ++rt) {
#pragma unroll
      for (int kk = 0; kk < 8; ++kk) {
        const float* p = latents + (size_t)(r0 + rt * 16) * D + kk * 32 + kb;
        float4 a0 = *(const float4*)p;
        float4 a1 = *(const float4*)(p + 4);
        short8 f;
        f[0] = (short)f2bf(a0.x); f[1] = (short)f2bf(a0.y);
        f[2] = (short)f2bf(a0.z); f[3] = (short)f2bf(a0.w);
        f[4] = (short)f2bf(a1.x); f[5] = (short)f2bf(a1.y);
        f[6] = (short)f2bf(a1.z); f[7] = (short)f2bf(a1.w);
        afr[rt][kk] = f;
      }
    }
  }

  float mval[4][4];
  int   midx[4][4];
#pragma unroll
  for (int rt = 0; rt < 4; ++rt)
#pragma unroll
    for (int i = 0; i < 4; ++i) { mval[rt][i] = 3.4e38f; midx[rt][i] = 0; }

  for (int ch = 0; ch < NCHUNK; ++ch) {
    // stage bf16 codebook chunk to LDS, swizzled: byte ^= (row&7)<<4
    const char* src = (const char*)(cb16 + (size_t)ch * KCHUNK * D);
#pragma unroll
    for (int i = 0; i < 16; ++i) {
      int g   = i * 128 + t;        // 0..2047 16B units
      int row = g >> 5;             // 32 units per 512B row
      int dc2 = (g & 31) * 16;
      int4v v = *(const int4v*)(src + row * 512 + dc2);
      int byte = (row * 512 + dc2) ^ ((row & 7) << 4);
      *(int4v*)(smem + byte) = v;
    }
    __syncthreads();

    for (int ct = 0; ct < 4; ++ct) {
      // B layout: lane holds B[(lane>>4)*8+j][lane&15] = cb[col][k] (both row-major, A·B^T)
      short8 bfr[8];
      const int brow = ct * 16 + (lane & 15);
      const int bb   = brow * 512 + (lane >> 4) * 16;
      const int sw   = (brow & 7) << 4;
#pragma unroll
      for (int kk = 0; kk < 8; ++kk)
        bfr[kk] = *(const short8*)(smem + ((bb + kk * 64) ^ sw));

      f32x4 acc[4] = {{0,0,0,0},{0,0,0,0},{0,0,0,0},{0,0,0,0}};
#pragma unroll
      for (int kk = 0; kk < 8; ++kk) {
#pragma unroll
        for (int rt = 0; rt < 4; ++rt)
          acc[rt] = __builtin_amdgcn_mfma_f32_16x16x32_bf16(afr[rt][kk], bfr[kk], acc[rt], 0, 0, 0);
      }

      const int col = ch * KCHUNK + ct * 16 + (lane & 15);
      const float cn = cnorm[col];          // L1/L2-resident
#pragma unroll
      for (int rt = 0; rt < 4; ++rt)
#pragma unroll
        for (int i = 0; i < 4; ++i) {
          float dv = cn - 2.0f * acc[rt][i];
          if (dv < mval[rt][i]) { mval[rt][i] = dv; midx[rt][i] = col; }
        }
    }
    __syncthreads();
  }

  // argmin reduce across the 16 lanes holding each row (first-index tie-break)
#pragma unroll
  for (int rt = 0; rt < 4; ++rt)
#pragma unroll
    for (int i = 0; i < 4; ++i) {
      float v = mval[rt][i]; int ix = midx[rt][i];
#pragma unroll
      for (int o = 1; o < 16; o <<= 1) {
        float ov = __shfl_xor(v, o);
        int   oi = __shfl_xor(ix, o);
        if (ov < v || (ov == v && oi < ix)) { v = ov; ix = oi; }
      }
      if ((lane & 15) == 0) {
        int rloc = w * RPW + rt * 16 + (lane >> 4) * 4 + i;
        s_inds[rloc] = ix;
      }
    }
  __syncthreads();

  // gather fp32 codebook rows, write quantized, accumulate loss partial
  float lsum = 0.f;
  for (int r = 0; r < RPW; ++r) {
    int rloc = w * RPW + r;
    int ind  = s_inds[rloc];
    size_t go = (size_t)(rowbase + rloc) * D + lane * 4;
    float4 q = *(const float4*)(cb32 + (size_t)ind * D + lane * 4);
    float4 x = *(const float4*)(latents + go);
    *(float4*)(out + go) = q;
    float dx = q.x - x.x, dy = q.y - x.y, dz = q.z - x.z, dw = q.w - x.w;
    lsum += dx*dx + dy*dy + dz*dz + dw*dw;
  }
#pragma unroll
  for (int o = 32; o; o >>= 1) lsum += __shfl_xor(lsum, o);
  if (lane == 0) s_part[w] = lsum;
  __syncthreads();
  if (t == 0) partials[blk] = s_part[0] + s_part[1];
}

// ---- pass 3: deterministic reduction of 256 block partials -> vq_loss ----
__global__ void vq_finalize(const float* __restrict__ partials,
                            float* __restrict__ out_loss) {
  __shared__ float sp[4];
  int t = threadIdx.x;     // 256
  float v = partials[t];
#pragma unroll
  for (int o = 32; o; o >>= 1) v += __shfl_xor(v, o);
  if ((t & 63) == 0) sp[t >> 6] = v;
  __syncthreads();
  if (t == 0) out_loss[0] = (sp[0] + sp[1] + sp[2] + sp[3]) * (1.25f / 8388608.0f);
}

extern "C" void kernel_launch(void* const* d_in, const int* in_sizes, int n_in,
                              void* d_out, int out_size, void* d_ws, size_t ws_size,
                              hipStream_t stream) {
  const float* latents  = (const float*)d_in[0];
  const float* codebook = (const float*)d_in[1];
  float* out = (float*)d_out;
  char*  ws  = (char*)d_ws;
  unsigned short* cb16   = (unsigned short*)ws;                         // 2 MB
  float* cnorm           = (float*)(ws + (2u << 20));                   // 16 KB
  float* partials        = (float*)(ws + (2u << 20) + (16u << 10));     // 1 KB

  vq_prep<<<KCODES, 64, 0, stream>>>(codebook, cb16, cnorm);
  vq_main<<<NBLK, 128, 0, stream>>>(latents, cb16, cnorm, codebook, out, partials);
  vq_finalize<<<1, 256, 0, stream>>>(partials, out + (size_t)NROWS * D);
}

// Round 2
// 102.412 us; speedup vs baseline: 5.9659x; 5.9659x over previous
//
#include <hip/hip_runtime.h>
#include <stdint.h>
#include <stddef.h>

#define D       256
#define KCODES  4096
#define NROWS   32768        // 16*2048
#define KSPLIT  2
#define KHALF   (KCODES / KSPLIT)    // 2048
#define KCHUNK  64
#define NCHUNK  (KHALF / KCHUNK)     // 32
#define MTILE   128                  // rows per block (4 waves * 32)
#define RPW     32                   // rows per wave
#define NRB     (NROWS / MTILE)      // 256 row-blocks

typedef __attribute__((ext_vector_type(8))) short short8;
typedef __attribute__((ext_vector_type(4))) float f32x4;

typedef const __attribute__((address_space(1))) void GV;
typedef __attribute__((address_space(3))) void LV;

__device__ inline unsigned int f2bf(float f) {
  union { float f; unsigned int u; } v; v.f = f;
  unsigned int r = v.u + 0x7FFFu + ((v.u >> 16) & 1u);   // RNE
  return r >> 16;
}

// ---- pass 1: codebook fp32 -> bf16, and ||c_k||^2 ----
__global__ void vq_prep(const float* __restrict__ cb,
                        unsigned short* __restrict__ cb16,
                        float* __restrict__ cnorm) {
  int row = blockIdx.x;         // 4096 blocks, one wave each
  int lane = threadIdx.x;       // 64
  float4 v = *(const float4*)(cb + (size_t)row * D + lane * 4);
  float s = v.x*v.x + v.y*v.y + v.z*v.z + v.w*v.w;
  uint2 p;
  p.x = f2bf(v.x) | (f2bf(v.y) << 16);
  p.y = f2bf(v.z) | (f2bf(v.w) << 16);
  *(uint2*)(cb16 + (size_t)row * D + lane * 4) = p;
#pragma unroll
  for (int o = 32; o; o >>= 1) s += __shfl_xor(s, o);
  if (lane == 0) cnorm[row] = s;
}

// ---- pass 2: distance-GEMM + per-K-slice argmin partials ----
// grid = 512: blockIdx & 255 = row-tile, blockIdx >> 8 = K-slice.
// (slices of one row-tile land on the SAME XCD: 256 % 8 == 0 -> latents L2-shared)
__global__ __launch_bounds__(256, 2) void vq_main(
    const float* __restrict__ latents,
    const unsigned short* __restrict__ cb16,
    const float* __restrict__ cnorm,
    float* __restrict__ pvals,
    int* __restrict__ pidx)
{
  __shared__ char smem[32 * 1024];   // [64 rows][512B] bf16 chunk, XOR-swizzled

  const int t    = threadIdx.x;
  const int lane = t & 63;
  const int w    = t >> 6;
  const int rb   = blockIdx.x & (NRB - 1);
  const int ks   = blockIdx.x >> 8;
  const int rowbase = rb * MTILE;

  // A fragments from global (fp32 -> bf16), resident in regs.
  // MFMA 16x16x32 A layout: lane holds A[lane&15][(lane>>4)*8 + j].
  short8 afr[2][8];
  {
    const int r0 = rowbase + w * RPW + (lane & 15);
    const int kb = (lane >> 4) * 8;
#pragma unroll
    for (int rt = 0; rt < 2; ++rt) {
#pragma unroll
      for (int kk = 0; kk < 8; ++kk) {
        const float* p = latents + (size_t)(r0 + rt * 16) * D + kk * 32 + kb;
        float4 a0 = *(const float4*)p;
        float4 a1 = *(const float4*)(p + 4);
        short8 f;
        f[0] = (short)f2bf(a0.x); f[1] = (short)f2bf(a0.y);
        f[2] = (short)f2bf(a0.z); f[3] = (short)f2bf(a0.w);
        f[4] = (short)f2bf(a1.x); f[5] = (short)f2bf(a1.y);
        f[6] = (short)f2bf(a1.z); f[7] = (short)f2bf(a1.w);
        afr[rt][kk] = f;
      }
    }
  }

  float mval[2][4];
  int   midx[2][4];
#pragma unroll
  for (int rt = 0; rt < 2; ++rt)
#pragma unroll
    for (int i = 0; i < 4; ++i) { mval[rt][i] = 3.4e38f; midx[rt][i] = 0; }

  const char* srcbase = (const char*)(cb16 + (size_t)ks * KHALF * D);

  for (int ch = 0; ch < NCHUNK; ++ch) {
    const char* src = srcbase + (size_t)ch * KCHUNK * D * 2;
    // async stage, pre-swizzled source so LDS holds the swizzled layout:
    // LDS[o] = G[swz(o)], swz(o) = o ^ (((o>>9)&7)<<4)  (involution)
#pragma unroll
    for (int i = 0; i < 8; ++i) {
      int ldsbase = i * 4096 + w * 1024;          // wave-uniform dest
      int lin     = i * 4096 + t * 16;            // this lane's dest slot
      int g       = lin ^ (((lin >> 9) & 7) << 4);
      __builtin_amdgcn_global_load_lds((GV*)(src + g), (LV*)(smem + ldsbase), 16, 0, 0);
    }
    __syncthreads();

    for (int ct = 0; ct < 4; ++ct) {
      // B layout: lane holds B[(lane>>4)*8+j][lane&15] = cb[col][k]
      short8 bfr[8];
      const int brow = ct * 16 + (lane & 15);
      const int bb   = brow * 512 + (lane >> 4) * 16;
      const int sw   = (brow & 7) << 4;
#pragma unroll
      for (int kk = 0; kk < 8; ++kk)
        bfr[kk] = *(const short8*)(smem + ((bb + kk * 64) ^ sw));

      f32x4 acc[2] = {{0,0,0,0},{0,0,0,0}};
#pragma unroll
      for (int kk = 0; kk < 8; ++kk) {
#pragma unroll
        for (int rt = 0; rt < 2; ++rt)
          acc[rt] = __builtin_amdgcn_mfma_f32_16x16x32_bf16(afr[rt][kk], bfr[kk], acc[rt], 0, 0, 0);
      }

      const int col = ks * KHALF + ch * KCHUNK + ct * 16 + (lane & 15);
      const float cn = cnorm[col];
#pragma unroll
      for (int rt = 0; rt < 2; ++rt)
#pragma unroll
        for (int i = 0; i < 4; ++i) {
          float dv = cn - 2.0f * acc[rt][i];
          if (dv < mval[rt][i]) { mval[rt][i] = dv; midx[rt][i] = col; }
        }
    }
    __syncthreads();
  }

  // argmin reduce across the 16 lanes of each row (first-index tie-break)
#pragma unroll
  for (int rt = 0; rt < 2; ++rt)
#pragma unroll
    for (int i = 0; i < 4; ++i) {
      float v = mval[rt][i]; int ix = midx[rt][i];
#pragma unroll
      for (int o = 1; o < 16; o <<= 1) {
        float ov = __shfl_xor(v, o);
        int   oi = __shfl_xor(ix, o);
        if (ov < v || (ov == v && oi < ix)) { v = ov; ix = oi; }
      }
      if ((lane & 15) == 0) {
        int row = rowbase + w * RPW + rt * 16 + (lane >> 4) * 4 + i;
        pvals[ks * NROWS + row] = v;
        pidx [ks * NROWS + row] = ix;
      }
    }
}

// ---- pass 3: merge K-slices, gather fp32 codebook, write out, loss partials ----
__global__ void vq_gather(const float* __restrict__ latents,
                          const float* __restrict__ cb32,
                          const float* __restrict__ pvals,
                          const int* __restrict__ pidx,
                          float* __restrict__ out,
                          float* __restrict__ partials)
{
  __shared__ float s_part[4];
  const int t = threadIdx.x, lane = t & 63, w = t >> 6;
  const int rowbase = blockIdx.x * MTILE + w * RPW;

  float lsum = 0.f;
  for (int r = 0; r < RPW; ++r) {
    int row = rowbase + r;
    float v0 = pvals[row], v1 = pvals[NROWS + row];
    int   i0 = pidx[row],  i1 = pidx[NROWS + row];
    int ind = (v1 < v0) ? i1 : i0;   // strict < : ties -> slice 0 (smaller index)
    size_t go = (size_t)row * D + lane * 4;
    float4 q = *(const float4*)(cb32 + (size_t)ind * D + lane * 4);
    float4 x = *(const float4*)(latents + go);
    *(float4*)(out + go) = q;
    float dx = q.x - x.x, dy = q.y - x.y, dz = q.z - x.z, dw = q.w - x.w;
    lsum += dx*dx + dy*dy + dz*dz + dw*dw;
  }
#pragma unroll
  for (int o = 32; o; o >>= 1) lsum += __shfl_xor(lsum, o);
  if (lane == 0) s_part[w] = lsum;
  __syncthreads();
  if (t == 0) partials[blockIdx.x] = s_part[0] + s_part[1] + s_part[2] + s_part[3];
}

// ---- pass 4: deterministic reduction of 256 block partials -> vq_loss ----
__global__ void vq_finalize(const float* __restrict__ partials,
                            float* __restrict__ out_loss) {
  __shared__ float sp[4];
  int t = threadIdx.x;     // 256
  float v = partials[t];
#pragma unroll
  for (int o = 32; o; o >>= 1) v += __shfl_xor(v, o);
  if ((t & 63) == 0) sp[t >> 6] = v;
  __syncthreads();
  if (t == 0) out_loss[0] = (sp[0] + sp[1] + sp[2] + sp[3]) * (1.25f / 8388608.0f);
}

extern "C" void kernel_launch(void* const* d_in, const int* in_sizes, int n_in,
                              void* d_out, int out_size, void* d_ws, size_t ws_size,
                              hipStream_t stream) {
  const float* latents  = (const float*)d_in[0];
  const float* codebook = (const float*)d_in[1];
  float* out = (float*)d_out;
  char*  ws  = (char*)d_ws;
  unsigned short* cb16 = (unsigned short*)ws;                          // 2 MB
  float* cnorm    = (float*)(ws + (2u << 20));                         // 16 KB
  float* pvals    = (float*)(ws + (2u << 20) + (16u << 10));           // 256 KB
  int*   pidx     = (int*)  (ws + (2u << 20) + (272u << 10));          // 256 KB
  float* partials = (float*)(ws + (2u << 20) + (528u << 10));          // 1 KB

  vq_prep<<<KCODES, 64, 0, stream>>>(codebook, cb16, cnorm);
  vq_main<<<NRB * KSPLIT, 256, 0, stream>>>(latents, cb16, cnorm, pvals, pidx);
  vq_gather<<<NRB, 256, 0, stream>>>(latents, codebook, pvals, pidx, out, partials);
  vq_finalize<<<1, 256, 0, stream>>>(partials, out + (size_t)NROWS * D);
}